// Round 7
// baseline (217.242 us; speedup 1.0000x reference)
//
#include <hip/hip_runtime.h>

#define DEV __device__ __forceinline__

typedef __attribute__((ext_vector_type(8))) short short8;
typedef __attribute__((ext_vector_type(4))) float f32x4;

DEV short f2bf(float x) {
  unsigned u = __float_as_uint(x);
  unsigned r = (u + 0x7fffu + ((u >> 16) & 1u)) >> 16;
  return (short)r;
}
DEV float bf2f(short x) {
  return __uint_as_float(((unsigned)(unsigned short)x) << 16);
}

DEV void gload_lds16(const void* g, void* l) {
  __builtin_amdgcn_global_load_lds((const __attribute__((address_space(1))) void*)g,
                                   (__attribute__((address_space(3))) void*)l, 16, 0, 0);
}

// ---------- fused fp32 -> bf16 convert (q,k,v,Wq,Wk,Wv) + zero-init of Mb ----------
__global__ __launch_bounds__(256) void cvt_all(
    const float* __restrict__ s0, const float* __restrict__ s1,
    const float* __restrict__ s2, const float* __restrict__ s3,
    const float* __restrict__ s4, const float* __restrict__ s5,
    short* __restrict__ d0, short* __restrict__ d1, short* __restrict__ d2,
    short* __restrict__ d3, short* __restrict__ d4, short* __restrict__ d5,
    float* __restrict__ Mb) {
  int g = blockIdx.x * 256 + threadIdx.x;
  if (g >= 1966080) {  // Mb zero-init (kv_outer atomics need zeros; ws is poisoned 0xAA)
    int off = g - 1966080;
    float4 z = {0.f, 0.f, 0.f, 0.f};
    float4* p = reinterpret_cast<float4*>(Mb) + (size_t)off * 2;
    p[0] = z;
    p[1] = z;
    return;
  }
  const float* s;
  short* d;
  int off;
  if (g < 524288) { s = s0; d = d0; off = g; }
  else if (g < 1048576) { s = s1; d = d1; off = g - 524288; }
  else if (g < 1572864) { s = s2; d = d2; off = g - 1048576; }
  else {
    int w2 = g - 1572864;
    int seg = w2 >> 17;
    off = w2 & 131071;
    s = seg == 0 ? s3 : seg == 1 ? s4 : s5;
    d = seg == 0 ? d3 : seg == 1 ? d4 : d5;
  }
  const float4* p = reinterpret_cast<const float4*>(s) + (size_t)off * 2;
  float4 a = p[0], b = p[1];
  short8 o;
  o[0] = f2bf(a.x); o[1] = f2bf(a.y); o[2] = f2bf(a.z); o[3] = f2bf(a.w);
  o[4] = f2bf(b.x); o[5] = f2bf(b.y); o[6] = f2bf(b.z); o[7] = f2bf(b.w);
  *reinterpret_cast<short8*>(d + (size_t)off * 8) = o;
}

// ---------- bf16 MFMA GEMM, 64x64 tile, 2-PHASE double-buffered ----------
// C[M,1024] = A[M,1024] @ W[1024,1024]^T. BM=BN=BK=64; 256 threads = 4 waves (2x2);
// wave tile 32x32 (2x2 frags of 16x16x32). LDS 2x(8+8) KB = 32 KB -> 5 blocks/CU.
// Schedule (T3 minimum, one barrier per K-step):
//   STAGE(buf0, kt=0); sync;
//   loop: STAGE(buf^1, kt+1) -> COMPUTE(buf) -> sync (drains vmcnt+lgkm) -> swap.
// Stage for tile t+1 is issued BEFORE tile t's compute, so gload_lds latency hides
// under ds_read+MFMA instead of being exposed in a vmcnt(0) drain (R6: 2-barrier
// structure plateaued at MfmaUtil 23% across all tile shapes).
// Race-free: reads of a buffer finish at the barrier (lgkmcnt drained) before the
// overwriting STAGE in the next iteration; stage completes (vmcnt drained) at the
// barrier before its first read. XCD-chunked swizzle + k-slot XOR swizzle as before.
template <typename OutT>
__global__ __launch_bounds__(256, 8) void gemm64(const short* __restrict__ A,
                                                 const short* __restrict__ W,
                                                 OutT* __restrict__ C,
                                                 long strideA, long strideW, long strideC) {
  __shared__ short At[2][64 * 64];
  __shared__ short Bt[2][64 * 64];
  const int nx = gridDim.x, ny = gridDim.y;
  int flat = blockIdx.x + nx * (blockIdx.y + ny * blockIdx.z);
  int nwg = nx * ny * gridDim.z;
  int l2 = (flat & 7) * (nwg >> 3) + (flat >> 3);  // grid %8==0 for all launches
  int colB = l2 % nx;
  int tmp = l2 / nx;
  int rowB = tmp % ny;
  int zB = tmp / ny;

  const short* Ab = A + (size_t)zB * strideA;
  const short* Wb = W + (size_t)zB * strideW;
  OutT* Cb = C + (size_t)zB * strideC;
  const int t = threadIdx.x;
  const int w = t >> 6;
  const int l = t & 63;
  const int lg = l >> 4, lr = l & 15;
  const int wm = w >> 1, wn = w & 1;
  const int rowBase = rowB * 64;
  const int colBase = colB * 64;

  // per-thread staging geometry, invariant over kt (2 A-chunks + 2 B-chunks of 16B)
  int cC[2];
  size_t gA[2], gB[2];
#pragma unroll
  for (int i = 0; i < 2; ++i) {
    int c = w * 128 + i * 64 + l;  // chunk id in [0,512)
    int r = c >> 3, s = c & 7;
    cC[i] = c;
    size_t swz = (size_t)((s ^ (r & 7)) << 3);
    gA[i] = (size_t)(rowBase + r) * 1024 + swz;
    gB[i] = (size_t)(colBase + r) * 1024 + swz;
  }

#define STAGE(buf, kt)                                              \
  {                                                                 \
    const int k0_ = (kt) * 64;                                      \
    _Pragma("unroll") for (int i = 0; i < 2; ++i) {                 \
      gload_lds16(Ab + gA[i] + k0_, &At[buf][cC[i] * 8]);           \
      gload_lds16(Wb + gB[i] + k0_, &Bt[buf][cC[i] * 8]);           \
    }                                                               \
  }

#define COMPUTE(buf)                                                          \
  {                                                                           \
    _Pragma("unroll") for (int kk = 0; kk < 2; ++kk) {                        \
      short8 afr[2], bfr[2];                                                  \
      _Pragma("unroll") for (int m = 0; m < 2; ++m) {                         \
        int ar = wm * 32 + m * 16 + lr;                                       \
        int slot = (kk * 4 + lg) ^ (ar & 7);                                  \
        afr[m] = *reinterpret_cast<const short8*>(&At[buf][ar * 64 + slot * 8]); \
      }                                                                       \
      _Pragma("unroll") for (int n = 0; n < 2; ++n) {                         \
        int br = wn * 32 + n * 16 + lr;                                       \
        int slot = (kk * 4 + lg) ^ (br & 7);                                  \
        bfr[n] = *reinterpret_cast<const short8*>(&Bt[buf][br * 64 + slot * 8]); \
      }                                                                       \
      _Pragma("unroll") for (int m = 0; m < 2; ++m)                           \
          _Pragma("unroll") for (int n = 0; n < 2; ++n)                       \
              acc[m][n] = __builtin_amdgcn_mfma_f32_16x16x32_bf16(            \
                  afr[m], bfr[n], acc[m][n], 0, 0, 0);                        \
    }                                                                         \
  }

  f32x4 acc[2][2] = {};

  STAGE(0, 0);
  __syncthreads();  // buf0 ready (vmcnt drained by syncthreads)
  for (int kt2 = 0; kt2 < 8; ++kt2) {  // 16 K-steps, 2 per iteration
    STAGE(1, kt2 * 2 + 1);
    COMPUTE(0);
    __syncthreads();  // buf1 ready; all reads of buf0 done
    if (kt2 < 7) STAGE(0, kt2 * 2 + 2);
    COMPUTE(1);
    __syncthreads();  // buf0 ready; all reads of buf1 done
  }
#undef STAGE
#undef COMPUTE

  // epilogue: C/D layout col = lane&15, row = (lane>>4)*4 + j
#pragma unroll
  for (int m = 0; m < 2; ++m)
#pragma unroll
    for (int n = 0; n < 2; ++n) {
      int row0 = rowBase + wm * 32 + m * 16 + lg * 4;
      int col = colBase + wn * 32 + n * 16 + lr;
#pragma unroll
      for (int j = 0; j < 4; ++j) {
        float v = acc[m][n][j];
        if constexpr (sizeof(OutT) == 2)
          Cb[(size_t)(row0 + j) * 1024 + col] = (OutT)f2bf(v);
        else
          Cb[(size_t)(row0 + j) * 1024 + col] = (OutT)v;
      }
    }
}

// ---------- M[b][h] = K_bh^T V_bh / 8  (fp32, split-S atomics; Mb pre-zeroed) ----------
__global__ __launch_bounds__(256) void kv_outer(const short* __restrict__ Kp,
                                                const short* __restrict__ Vp,
                                                float* __restrict__ Mb) {
  __shared__ float Ks[128][64];
  __shared__ float Vs[128][64];
  const int t = threadIdx.x;
  const int sc = blockIdx.x, h = blockIdx.y, b = blockIdx.z;
  const size_t base = ((size_t)(b * 2048 + sc * 128)) * 1024 + h * 64;
  for (int e = t; e < 128 * 64; e += 256) {
    int r = e >> 6, c = e & 63;
    size_t g = base + (size_t)r * 1024 + c;
    Ks[r][c] = bf2f(Kp[g]);
    Vs[r][c] = bf2f(Vp[g]);
  }
  __syncthreads();
  const int dp0 = (t >> 4) * 4, d0 = (t & 15) * 4;
  float acc[4][4] = {};
  for (int s = 0; s < 128; ++s) {
    float4 kv = *reinterpret_cast<const float4*>(&Ks[s][dp0]);
    float4 vv = *reinterpret_cast<const float4*>(&Vs[s][d0]);
    float ka[4] = {kv.x, kv.y, kv.z, kv.w};
    float va[4] = {vv.x, vv.y, vv.z, vv.w};
#pragma unroll
    for (int i = 0; i < 4; ++i)
#pragma unroll
      for (int j = 0; j < 4; ++j) acc[i][j] += ka[i] * va[j];
  }
  float* dst = Mb + (size_t)(b * 16 + h) * 4096;
#pragma unroll
  for (int i = 0; i < 4; ++i)
#pragma unroll
    for (int j = 0; j < 4; ++j)
      atomicAdd(&dst[(dp0 + i) * 64 + d0 + j], acc[i][j] * 0.125f);
}

// ---------- W2T[b][j][h*64+d'] = sum_d M_bh[d'][d] * Wo_f32[j][h*64+d]  (bf16 out) ----------
__global__ __launch_bounds__(256) void make_w2t(const float* __restrict__ Mb,
                                                const float* __restrict__ Wo,
                                                short* __restrict__ W2T) {
  __shared__ float Ms[64][65];
  __shared__ float Wos[64][64];
  const int t = threadIdx.x;
  const int jc = blockIdx.x, h = blockIdx.y, b = blockIdx.z;
  const float* Msrc = Mb + (size_t)(b * 16 + h) * 4096;
  for (int e = t; e < 4096; e += 256) {
    int r = e >> 6, c = e & 63;
    Ms[r][c] = Msrc[e];
    Wos[r][c] = Wo[(size_t)(jc * 64 + r) * 1024 + h * 64 + c];
  }
  __syncthreads();
  const int j0 = (t >> 4) * 4, p0 = (t & 15) * 4;
  float acc[4][4] = {};
  for (int d = 0; d < 64; ++d) {
    float wv[4], mv[4];
#pragma unroll
    for (int i = 0; i < 4; ++i) { wv[i] = Wos[j0 + i][d]; mv[i] = Ms[p0 + i][d]; }
#pragma unroll
    for (int i = 0; i < 4; ++i)
#pragma unroll
      for (int j2 = 0; j2 < 4; ++j2) acc[i][j2] += wv[i] * mv[j2];
  }
  short* dst = W2T + (size_t)b * 1048576;
#pragma unroll
  for (int i = 0; i < 4; ++i)
#pragma unroll
    for (int j2 = 0; j2 < 4; ++j2)
      dst[(size_t)(jc * 64 + j0 + i) * 1024 + h * 64 + p0 + j2] = f2bf(acc[i][j2]);
}

extern "C" void kernel_launch(void* const* d_in, const int* in_sizes, int n_in,
                              void* d_out, int out_size, void* d_ws, size_t ws_size,
                              hipStream_t stream) {
  const float* q  = (const float*)d_in[0];
  const float* k  = (const float*)d_in[1];
  const float* v  = (const float*)d_in[2];
  // d_in[3] = mask: no-op in the reference
  const float* Wq = (const float*)d_in[4];
  const float* Wk = (const float*)d_in[5];
  const float* Wv = (const float*)d_in[6];
  const float* Wo = (const float*)d_in[7];
  float* out = (float*)d_out;
  char* ws = (char*)d_ws;

  // workspace layout (~60 MiB)
  short* qkv = (short*)(ws);                  // 24 MiB: q,k,v bf16 contiguous (4M elems each)
  short* qb = qkv;
  short* kb = qkv + (size_t)4194304;
  short* vb = qkv + (size_t)8388608;
  short* wb = (short*)(ws + (24l << 20));     // 6 MiB: Wq,Wk,Wv bf16 (1M elems each)
  short* wqb = wb;
  short* wkb = wb + 1048576;
  short* wvb = wb + 2097152;
  short* Pp = (short*)(ws + (30l << 20));     // 24 MiB: Qp,Kp,Vp bf16 contiguous
  short* Qp = Pp;
  short* Kp = Pp + (size_t)4194304;
  short* Vp = Pp + (size_t)8388608;
  float* Mb  = (float*)(ws + (54l << 20));    // 512 KiB
  short* W2T = (short*)(ws + (55l << 20));    // 4 MiB

  // 1) convert q,k,v,Wq,Wk,Wv to bf16 + zero Mb
  cvt_all<<<7744, 256, 0, stream>>>(q, k, v, Wq, Wk, Wv,
                                    qb, kb, vb, wqb, wkb, wvb, Mb);

  // 2) Q/K/V projections, one z-batched launch: 16x64x3 = 3072 blocks
  gemm64<short><<<dim3(16, 64, 3), 256, 0, stream>>>(
      qkv, wb, Pp, 4194304l, 1048576l, 4194304l);

  // 3) per-head K^T V / 8
  kv_outer<<<dim3(16, 16, 2), 256, 0, stream>>>(Kp, Vp, Mb);

  // 4) fold blockdiag(M) into Wo (reads fp32 Wo directly)
  make_w2t<<<dim3(16, 16, 2), 256, 0, stream>>>(Mb, Wo, W2T);

  // 5) out[b] = Qp[b] @ W2T[b]^T  (16x32x2 = 1024 blocks)
  gemm64<float><<<dim3(16, 32, 2), 256, 0, stream>>>(
      Qp, W2T, out, 2097152l, 1048576l, 2097152l);
}